// Round 7
// baseline (178.635 us; speedup 1.0000x reference)
//
#include <hip/hip_runtime.h>
#include <hip/hip_bf16.h>

typedef __hip_bfloat16 bh;
typedef __attribute__((ext_vector_type(8))) __bf16 bf16x8;
typedef __attribute__((ext_vector_type(4))) float f32x4;
typedef __attribute__((ext_vector_type(4))) int i32x4;
typedef __attribute__((ext_vector_type(4))) short s16x4;

#define NB 2
#define NL 4096
#define NC 512
#define NH 8
#define NDH 64
#define NM (NB * NL)          // 8192
#define LOG2E 1.4426950408889634f
#define KVBLK 8192            // elems per (bh,kt): 8KB K frags + 8KB V frags

static __device__ __forceinline__ f32x4 mfma_bf16(bf16x8 a, bf16x8 b, f32x4 c) {
    return __builtin_amdgcn_mfma_f32_16x16x32_bf16(a, b, c, 0, 0, 0);
}

static __device__ __forceinline__ void st_bf4(bh* dst, float a, float b, float c, float d) {
    bh tmp[4] = {__float2bfloat16(a), __float2bfloat16(b),
                 __float2bfloat16(c), __float2bfloat16(d)};
    *(s16x4*)dst = *(const s16x4*)tmp;
}
static __device__ __forceinline__ bf16x8 pk_bf8(float a0, float a1, float a2, float a3,
                                                float b0, float b1, float b2, float b3) {
    bh tmp[8] = {__float2bfloat16(a0), __float2bfloat16(a1),
                 __float2bfloat16(a2), __float2bfloat16(a3),
                 __float2bfloat16(b0), __float2bfloat16(b1),
                 __float2bfloat16(b2), __float2bfloat16(b3)};
    return *(const bf16x8*)tmp;
}

static __device__ __forceinline__ void gload16(const bh* g, bh* l) {
    __builtin_amdgcn_global_load_lds(
        (const __attribute__((address_space(1))) void*)g,
        (__attribute__((address_space(3))) void*)l,
        16, 0, 0);
}

// ---------------------------------------------------------------------------
// Kernel 0: combined prep (unchanged).
// ---------------------------------------------------------------------------
__global__ __launch_bounds__(256, 2)
void prep(const float* __restrict__ x,
          const float* __restrict__ Wq, const float* __restrict__ Wk,
          const float* __restrict__ Wv, const float* __restrict__ Wo,
          bh* __restrict__ xf, bh* __restrict__ Wf)
{
    const int t = threadIdx.x;
    const int wave = t >> 6, lane = t & 63;
    const int quad = lane >> 4, c16 = lane & 15;

    if (blockIdx.z < 8) {
        __shared__ __align__(16) bh T[64][72];
        const int m64 = blockIdx.x, k64 = blockIdx.z;
        #pragma unroll
        for (int rep = 0; rep < 4; rep++) {
            int li = t + rep * 256;
            int r = li >> 4, c4 = (li & 15) * 4;
            float4 f = *(const float4*)&x[(size_t)(m64 * 64 + r) * 512 + k64 * 64 + c4];
            st_bf4(&T[r][c4], f.x, f.y, f.z, f.w);
        }
        __syncthreads();
        #pragma unroll
        for (int kcl = 0; kcl < 2; kcl++) {
            i32x4 v = *(const i32x4*)&T[wave * 16 + c16][kcl * 32 + quad * 8];
            size_t addr = ((size_t)(m64 * 4 + wave) * 16 + (k64 * 2 + kcl)) * 512 + lane * 8;
            *(i32x4*)&xf[addr] = v;
        }
    } else {
        if (blockIdx.x >= 64) return;
        int task = blockIdx.x * 4 + wave;
        int z = task >> 6, nt = (task >> 3) & 7, k0i = task & 7;
        const float* W = (z == 0) ? Wq : (z == 1) ? Wk : (z == 2) ? Wv : Wo;
        bh* dst = Wf + (((size_t)z * 8 + nt) * 8 + k0i) * 4096;
        #pragma unroll
        for (int kc = 0; kc < 2; kc++)
            #pragma unroll
            for (int fn = 0; fn < 4; fn++) {
                bh tmp[8];
                #pragma unroll
                for (int j = 0; j < 8; j++)
                    tmp[j] = __float2bfloat16(
                        W[(size_t)(k0i * 64 + kc * 32 + quad * 8 + j) * 512
                          + nt * 64 + fn * 16 + c16]);
                *(i32x4*)&dst[(kc * 4 + fn) * 512 + lane * 8] = *(const i32x4*)tmp;
            }
    }
}

// ---------------------------------------------------------------------------
// Kernel 1: fused QKV projection, v2: M=64 per block, K-step 32, grid 1024
// -> 4 resident blocks/CU (32 KB LDS each) = 4 independent barrier domains
// (vs 2 lockstepped 80KB blocks).  One barrier per K-iter.  All global
// image layouts (xf, Wf, Qb, KVf) identical to the verified R4/R6 versions —
// only the block-local tiling changed.  Each wave owns one 16-row m-block.
// ---------------------------------------------------------------------------
__global__ __launch_bounds__(256, 4)
void qkv_gemm(const bh* __restrict__ xf, const bh* __restrict__ Wf,
              bh* __restrict__ Qb, bh* __restrict__ KVf)
{
    __shared__ __align__(16) bh smem[2][8192];   // per buf: Xl 2048 + Wl 6144 elems (16 KB)

    const int t = threadIdx.x;
    const int wave = t >> 6, lane = t & 63;
    const int quad = lane >> 4, c16 = lane & 15;
    const int m0 = blockIdx.x * 64;
    const int nt = blockIdx.y;
    const int m16b = m0 >> 4;

    f32x4 acc[3][4];
    for (int z = 0; z < 3; z++)
        for (int fn = 0; fn < 4; fn++)
            for (int u = 0; u < 4; u++) acc[z][fn][u] = 0.0f;

    auto stage = [&](int k32, int buf) {
        bh* Xl = &smem[buf][0];
        bh* Wl = &smem[buf][2048];
        // X frag-block (m16b + wave, k32); wave stages its own af block.
        gload16(xf + ((size_t)(m16b + wave) * 16 + k32) * 512 + lane * 8,
                &Xl[wave * 512 + lane * 8]);
        // W frag fn=wave of the current 32-k block, for each z.
        #pragma unroll
        for (int z = 0; z < 3; z++) {
            const bh* wz = Wf + (((size_t)z * 8 + nt) * 8 + (k32 >> 1)) * 4096
                         + (size_t)((k32 & 1) * 4 + wave) * 512;
            gload16(wz + lane * 8, &Wl[z * 2048 + wave * 512 + lane * 8]);
        }
    };

    stage(0, 0);
    for (int k32 = 0; k32 < 16; k32++) {
        const int buf = k32 & 1;
        __syncthreads();                  // loads for k32 landed; other buf free
        if (k32 < 15) stage(k32 + 1, buf ^ 1);
        const bh* Xl = &smem[buf][0];
        const bh* Wl = &smem[buf][2048];
        bf16x8 af = *(const bf16x8*)&Xl[wave * 512 + lane * 8];
        #pragma unroll
        for (int z = 0; z < 3; z++)
            #pragma unroll
            for (int fn = 0; fn < 4; fn++) {
                bf16x8 bf = *(const bf16x8*)&Wl[z * 2048 + fn * 512 + lane * 8];
                acc[z][fn] = mfma_bf16(af, bf, acc[z][fn]);
            }
    }
    __syncthreads();                      // drain before LDS reuse in epilogue

    const int h = nt;
    const int b = m0 >> 12;
    const int l0 = m0 & 4095;
    const int bh_i = b * NH + h;
    const int kt0 = l0 >> 6;              // exactly one 64-row kt tile per block

    // ---- Phase Q: LDS transpose, coalesced 16B stores to row-major Qb.
    {
        bh* Tq = &smem[0][0];             // 64 x 68
        #pragma unroll
        for (int i = 0; i < 4; i++) {
            int ll = wave * 16 + quad * 4 + i;
            #pragma unroll
            for (int fn = 0; fn < 4; fn++)
                Tq[ll * 68 + fn * 16 + c16] =
                    __float2bfloat16(acc[0][fn][i] * 0.125f);
        }
        __syncthreads();
        int l = t >> 2, part = t & 3;
        bh* dst = Qb + ((size_t)bh_i * NL + l0 + l) * NDH + part * 16;
        const bh* src = &Tq[l * 68 + part * 16];
        *(i32x4*)(dst)     = *(const i32x4*)(src);
        *(i32x4*)(dst + 8) = *(const i32x4*)(src + 8);
        __syncthreads();
    }

    // ---- Phase K: LDS scatter into the kt0 K-frag image (xLOG2E), copy-out.
    {
        bh* Tk = &smem[0][0];             // 4096 elems = one kt K-image
        #pragma unroll
        for (int i = 0; i < 4; i++) {
            int c16t = quad * 4 + i;      // key-within-16; fk = wave
            #pragma unroll
            for (int fn = 0; fn < 4; fn++) {
                int d = fn * 16 + c16;
                int kc = d >> 5, qt = (d >> 3) & 3, j = d & 7;
                Tk[(wave * 2 + kc) * 512 + (qt * 16 + c16t) * 8 + j] =
                    __float2bfloat16(acc[1][fn][i] * LOG2E);
            }
        }
        __syncthreads();
        int idx = t * 16;
        bh* dst = KVf + (size_t)(bh_i * 64 + kt0) * KVBLK + idx;
        *(i32x4*)(dst)     = *(const i32x4*)&Tk[idx];
        *(i32x4*)(dst + 8) = *(const i32x4*)&Tk[idx + 8];
    }

    // ---- V: 32-k interleaved frag stores (same sigma-image as R4/R6).
    // fkv (key-16-block within the kt tile) = wave.
    #pragma unroll
    for (int fn = 0; fn < 4; fn++) {
        size_t addr = (size_t)(bh_i * 64 + kt0) * KVBLK + 4096
                    + (size_t)(fn * 2 + (wave >> 1)) * 512 + lane * 8 + (wave & 1) * 4;
        st_bf4(&KVf[addr], acc[2][fn][0], acc[2][fn][1],
                           acc[2][fn][2], acc[2][fn][3]);
    }
}

// ---------------------------------------------------------------------------
// Kernel 2: flash attention — unchanged from R6 (verified): split-K, 512
// threads, K=32 PV via pre-permuted V image, XCD-chunked work swizzle.
// ---------------------------------------------------------------------------
__global__ __launch_bounds__(512, 4)
void flash_attn(const bh* __restrict__ Qb, const bh* __restrict__ KVf,
                bh* __restrict__ attb)
{
    __shared__ __align__(16) bh SF[2][2][KVBLK];   // [group][buf], 64 KB

    const int t = threadIdx.x;
    const int wave = t >> 6, lane = t & 63;
    const int group = wave >> 2, w4 = wave & 3;
    const int quad = lane >> 4, c16 = lane & 15;

    const int bid = blockIdx.x + blockIdx.y * 32;      // gridDim.x == 32
    const int work = (bid & 7) * 64 + (bid >> 3);      // bijective on [0,512)
    const int bh_idx = work >> 5;
    const int q0 = (work & 31) * 128;

    const bh* Qp  = Qb + (size_t)bh_idx * NL * NDH;
    const bh* KVp = KVf + (size_t)bh_idx * 64 * KVBLK;

    bf16x8 qf[2][2];
    #pragma unroll
    for (int fq = 0; fq < 2; fq++)
        #pragma unroll
        for (int kc = 0; kc < 2; kc++)
            qf[fq][kc] = *(const bf16x8*)
                &Qp[(size_t)(q0 + w4 * 32 + fq * 16 + c16) * NDH + kc * 32 + quad * 8];

    f32x4 ot[4][2];
    float lsum[2] = {0.0f, 0.0f};
    for (int a = 0; a < 4; a++)
        for (int fq = 0; fq < 2; fq++)
            for (int u = 0; u < 4; u++) ot[a][fq][u] = 0.0f;
    const f32x4 z4 = {0.0f, 0.0f, 0.0f, 0.0f};

    auto stage = [&](int i, int buf) {
        int kt = 2 * i + group;
        #pragma unroll
        for (int r = 0; r < 4; r++) {
            int off = (w4 * 4 + r) * 512 + lane * 8;
            gload16(KVp + (size_t)kt * KVBLK + off, &SF[group][buf][off]);
        }
    };

    stage(0, 0);
    for (int i = 0; i < 32; i++) {
        const int buf = i & 1;
        __syncthreads();
        if (i < 31) stage(i + 1, buf ^ 1);
        const bh* sf = &SF[group][buf][0];

        f32x4 s[4][2];
        #pragma unroll
        for (int fk = 0; fk < 4; fk++) {
            bf16x8 kf0 = *(const bf16x8*)&sf[(fk * 2 + 0) * 512 + lane * 8];
            s[fk][0] = mfma_bf16(kf0, qf[0][0], z4);
            s[fk][1] = mfma_bf16(kf0, qf[1][0], z4);
        }
        #pragma unroll
        for (int fk = 0; fk < 4; fk++) {
            bf16x8 kf1 = *(const bf16x8*)&sf[(fk * 2 + 1) * 512 + lane * 8];
            s[fk][0] = mfma_bf16(kf1, qf[0][1], s[fk][0]);
            s[fk][1] = mfma_bf16(kf1, qf[1][1], s[fk][1]);
        }

        bf16x8 vt[4][2];
        #pragma unroll
        for (int fn = 0; fn < 4; fn++)
            #pragma unroll
            for (int a = 0; a < 2; a++)
                vt[fn][a] = *(const bf16x8*)&sf[4096 + (fn * 2 + a) * 512 + lane * 8];

        float rs0 = 0.0f, rs1 = 0.0f;
        #pragma unroll
        for (int a = 0; a < 2; a++) {
            float a0 = __builtin_amdgcn_exp2f(s[2 * a][0][0]);
            float a1 = __builtin_amdgcn_exp2f(s[2 * a][0][1]);
            float a2 = __builtin_amdgcn_exp2f(s[2 * a][0][2]);
            float a3 = __builtin_amdgcn_exp2f(s[2 * a][0][3]);
            float a4 = __builtin_amdgcn_exp2f(s[2 * a + 1][0][0]);
            float a5 = __builtin_amdgcn_exp2f(s[2 * a + 1][0][1]);
            float a6 = __builtin_amdgcn_exp2f(s[2 * a + 1][0][2]);
            float a7 = __builtin_amdgcn_exp2f(s[2 * a + 1][0][3]);
            rs0 += ((a0 + a1) + (a2 + a3)) + ((a4 + a5) + (a6 + a7));
            bf16x8 p0 = pk_bf8(a0, a1, a2, a3, a4, a5, a6, a7);
            float b0 = __builtin_amdgcn_exp2f(s[2 * a][1][0]);
            float b1 = __builtin_amdgcn_exp2f(s[2 * a][1][1]);
            float b2 = __builtin_amdgcn_exp2f(s[2 * a][1][2]);
            float b3 = __builtin_amdgcn_exp2f(s[2 * a][1][3]);
            float b4 = __builtin_amdgcn_exp2f(s[2 * a + 1][1][0]);
            float b5 = __builtin_amdgcn_exp2f(s[2 * a + 1][1][1]);
            float b6 = __builtin_amdgcn_exp2f(s[2 * a + 1][1][2]);
            float b7 = __builtin_amdgcn_exp2f(s[2 * a + 1][1][3]);
            rs1 += ((b0 + b1) + (b2 + b3)) + ((b4 + b5) + (b6 + b7));
            bf16x8 p1 = pk_bf8(b0, b1, b2, b3, b4, b5, b6, b7);
            #pragma unroll
            for (int fn = 0; fn < 4; fn++) {
                ot[fn][0] = mfma_bf16(vt[fn][a], p0, ot[fn][0]);
                ot[fn][1] = mfma_bf16(vt[fn][a], p1, ot[fn][1]);
            }
        }
        lsum[0] += rs0;
        lsum[1] += rs1;
    }

    #pragma unroll
    for (int fq = 0; fq < 2; fq++) {
        lsum[fq] += __shfl_xor(lsum[fq], 16);
        lsum[fq] += __shfl_xor(lsum[fq], 32);
    }

    float* Ocmb = (float*)&SF[0][0][0];
    float* Lcmb = Ocmb + 128 * 64;
    __syncthreads();
    if (group == 1) {
        #pragma unroll
        for (int fq = 0; fq < 2; fq++) {
            int q = w4 * 32 + fq * 16 + c16;
            #pragma unroll
            for (int fn = 0; fn < 4; fn++)
                *(f32x4*)&Ocmb[q * 64 + fn * 16 + quad * 4] = ot[fn][fq];
            if (quad == 0) Lcmb[q] = lsum[fq];
        }
    }
    __syncthreads();
    if (group == 0) {
        const int b = bh_idx >> 3, h = bh_idx & 7;
        const int mbase16 = (b * NL + q0) >> 4;
        #pragma unroll
        for (int fq = 0; fq < 2; fq++) {
            int q = w4 * 32 + fq * 16 + c16;
            float inv = 1.0f / (lsum[fq] + Lcmb[q]);
            int m16 = mbase16 + w4 * 2 + fq;
            #pragma unroll
            for (int fn = 0; fn < 4; fn++) {
                f32x4 o2 = *(const f32x4*)&Ocmb[q * 64 + fn * 16 + quad * 4];
                size_t addr = ((size_t)m16 * 16 + h * 2 + (fn >> 1)) * 512
                            + (size_t)(((fn & 1) * 2 + (quad >> 1)) * 16 + c16) * 8
                            + (quad & 1) * 4;
                st_bf4(&attb[addr],
                       (ot[fn][fq][0] + o2[0]) * inv, (ot[fn][fq][1] + o2[1]) * inv,
                       (ot[fn][fq][2] + o2[2]) * inv, (ot[fn][fq][3] + o2[3]) * inv);
            }
        }
    }
}

// ---------------------------------------------------------------------------
// Kernel 3: out = att(A-frag) @ Wo + bo -> fp32, v2: M=64 per block, K-step
// 32, grid 1024 -> 4 resident blocks/CU (16 KB LDS), 1 barrier/iter.
// ---------------------------------------------------------------------------
__global__ __launch_bounds__(256, 4)
void out_gemm(const bh* __restrict__ Af, const bh* __restrict__ Wf,
              const float* __restrict__ bo, float* __restrict__ out)
{
    __shared__ __align__(16) bh smem[2][4096];   // per buf: Xl 2048 + Wl 2048 (8 KB)

    const int t = threadIdx.x;
    const int wave = t >> 6, lane = t & 63;
    const int quad = lane >> 4, c16 = lane & 15;
    const int m0 = blockIdx.x * 64;
    const int nt = blockIdx.y;
    const int n0 = nt * 64;
    const int m16b = m0 >> 4;

    f32x4 acc[4];
    for (int fn = 0; fn < 4; fn++)
        for (int u = 0; u < 4; u++) acc[fn][u] = 0.0f;

    auto stage = [&](int k32, int buf) {
        bh* Xl = &smem[buf][0];
        bh* Wl = &smem[buf][2048];
        gload16(Af + ((size_t)(m16b + wave) * 16 + k32) * 512 + lane * 8,
                &Xl[wave * 512 + lane * 8]);
        const bh* wz = Wf + (((size_t)3 * 8 + nt) * 8 + (k32 >> 1)) * 4096
                     + (size_t)((k32 & 1) * 4 + wave) * 512;
        gload16(wz + lane * 8, &Wl[wave * 512 + lane * 8]);
    };

    stage(0, 0);
    for (int k32 = 0; k32 < 16; k32++) {
        const int buf = k32 & 1;
        __syncthreads();
        if (k32 < 15) stage(k32 + 1, buf ^ 1);
        const bh* Xl = &smem[buf][0];
        const bh* Wl = &smem[buf][2048];
        bf16x8 af = *(const bf16x8*)&Xl[wave * 512 + lane * 8];
        #pragma unroll
        for (int fn = 0; fn < 4; fn++) {
            bf16x8 bf = *(const bf16x8*)&Wl[fn * 512 + lane * 8];
            acc[fn] = mfma_bf16(af, bf, acc[fn]);
        }
    }

    #pragma unroll
    for (int i = 0; i < 4; i++) {
        int mr = m0 + wave * 16 + quad * 4 + i;
        #pragma unroll
        for (int fn = 0; fn < 4; fn++) {
            int cn = n0 + fn * 16 + c16;
            out[(size_t)mr * 512 + cn] = acc[fn][i] + bo[cn];
        }
    }
}

// ---------------------------------------------------------------------------
extern "C" void kernel_launch(void* const* d_in, const int* in_sizes, int n_in,
                              void* d_out, int out_size, void* d_ws, size_t ws_size,
                              hipStream_t stream)
{
    const float* x  = (const float*)d_in[0];
    const float* Wq = (const float*)d_in[1];
    const float* Wk = (const float*)d_in[2];
    const float* Wv = (const float*)d_in[3];
    const float* Wo = (const float*)d_in[4];
    const float* bo = (const float*)d_in[5];
    float* out = (float*)d_out;

    const size_t mat = (size_t)NM * NC;       // 4 Mi elems (8 MB bf16)
    bh* Qb   = (bh*)d_ws;                     //  8 MB
    bh* KVf  = Qb + mat;                      // 16 MB
    bh* attb = KVf + 2 * mat;                 //  8 MB (A-frag layout)
    bh* Wf   = attb + mat;                    //  2 MB
    bh* xf   = Wf + 4 * 8 * 8 * 4096;         //  8 MB

    prep      <<<dim3(128, 1, 9),         256, 0, stream>>>(x, Wq, Wk, Wv, Wo, xf, Wf);
    qkv_gemm  <<<dim3(NM / 64, NC / 64),  256, 0, stream>>>(xf, Wf, Qb, KVf);
    flash_attn<<<dim3(NL / 128, NB * NH), 512, 0, stream>>>(Qb, KVf, attb);
    out_gemm  <<<dim3(NM / 64, NC / 64),  256, 0, stream>>>(attb, Wf, bo, out);
}

// Round 8
// 178.102 us; speedup vs baseline: 1.0030x; 1.0030x over previous
//
#include <hip/hip_runtime.h>
#include <hip/hip_bf16.h>

typedef __hip_bfloat16 bh;
typedef __attribute__((ext_vector_type(8))) __bf16 bf16x8;
typedef __attribute__((ext_vector_type(4))) float f32x4;
typedef __attribute__((ext_vector_type(4))) int i32x4;
typedef __attribute__((ext_vector_type(4))) short s16x4;

#define NB 2
#define NL 4096
#define NC 512
#define NH 8
#define NDH 64
#define NM (NB * NL)          // 8192
#define LOG2E 1.4426950408889634f
#define KVBLK 8192            // elems per (bh,kt): 8KB K frags + 8KB V frags

static __device__ __forceinline__ f32x4 mfma_bf16(bf16x8 a, bf16x8 b, f32x4 c) {
    return __builtin_amdgcn_mfma_f32_16x16x32_bf16(a, b, c, 0, 0, 0);
}

static __device__ __forceinline__ void st_bf4(bh* dst, float a, float b, float c, float d) {
    bh tmp[4] = {__float2bfloat16(a), __float2bfloat16(b),
                 __float2bfloat16(c), __float2bfloat16(d)};
    *(s16x4*)dst = *(const s16x4*)tmp;
}
static __device__ __forceinline__ bf16x8 pk_bf8(float a0, float a1, float a2, float a3,
                                                float b0, float b1, float b2, float b3) {
    bh tmp[8] = {__float2bfloat16(a0), __float2bfloat16(a1),
                 __float2bfloat16(a2), __float2bfloat16(a3),
                 __float2bfloat16(b0), __float2bfloat16(b1),
                 __float2bfloat16(b2), __float2bfloat16(b3)};
    return *(const bf16x8*)tmp;
}

static __device__ __forceinline__ void gload16(const bh* g, bh* l) {
    __builtin_amdgcn_global_load_lds(
        (const __attribute__((address_space(1))) void*)g,
        (__attribute__((address_space(3))) void*)l,
        16, 0, 0);
}

// ---------------------------------------------------------------------------
// Kernel 0: prep v2 — W pack ONLY (x-transpose pass deleted; qkv now reads
// x directly).  Wq,Wk,Wv,Wo fp32 -> Wf B-frag blocks.  64 blocks.
// ---------------------------------------------------------------------------
__global__ __launch_bounds__(256, 2)
void prep(const float* __restrict__ Wq, const float* __restrict__ Wk,
          const float* __restrict__ Wv, const float* __restrict__ Wo,
          bh* __restrict__ Wf)
{
    const int t = threadIdx.x;
    const int wave = t >> 6, lane = t & 63;
    const int quad = lane >> 4, c16 = lane & 15;

    int task = blockIdx.x * 4 + wave;
    int z = task >> 6, nt = (task >> 3) & 7, k0i = task & 7;
    const float* W = (z == 0) ? Wq : (z == 1) ? Wk : (z == 2) ? Wv : Wo;
    bh* dst = Wf + (((size_t)z * 8 + nt) * 8 + k0i) * 4096;
    #pragma unroll
    for (int kc = 0; kc < 2; kc++)
        #pragma unroll
        for (int fn = 0; fn < 4; fn++) {
            bh tmp[8];
            #pragma unroll
            for (int j = 0; j < 8; j++)
                tmp[j] = __float2bfloat16(
                    W[(size_t)(k0i * 64 + kc * 32 + quad * 8 + j) * 512
                      + nt * 64 + fn * 16 + c16]);
            *(i32x4*)&dst[(kc * 4 + fn) * 512 + lane * 8] = *(const i32x4*)tmp;
        }
}

// ---------------------------------------------------------------------------
// Kernel 1: fused QKV projection v3 — A read DIRECTLY from x (fp32) into
// registers (per-lane 2x float4, contiguous; cvt in-reg).  A never touches
// LDS: in the M=64 tiling each wave's A-frag is private.  Only W is staged
// (shared across waves).  Reg double-buffer carries next iter's raw floats
// across the MFMA block so load latency hides under compute.  Epilogues
// (Q transpose, K scatter, V sigma-image) verbatim from R7 (verified).
// ---------------------------------------------------------------------------
__global__ __launch_bounds__(256, 4)
void qkv_gemm(const float* __restrict__ x, const bh* __restrict__ Wf,
              bh* __restrict__ Qb, bh* __restrict__ KVf)
{
    __shared__ __align__(16) bh smem[2][6144];   // W only: 12 KB per buf

    const int t = threadIdx.x;
    const int wave = t >> 6, lane = t & 63;
    const int quad = lane >> 4, c16 = lane & 15;
    const int m0 = blockIdx.x * 64;
    const int nt = blockIdx.y;

    // A source: row m0 + wave*16 + c16, k base quad*8 (matches old xf image)
    const float* xrow = x + (size_t)(m0 + wave * 16 + c16) * 512 + quad * 8;

    f32x4 acc[3][4];
    for (int z = 0; z < 3; z++)
        for (int fn = 0; fn < 4; fn++)
            for (int u = 0; u < 4; u++) acc[z][fn][u] = 0.0f;

    auto stageW = [&](int k32, int buf) {
        bh* Wl = &smem[buf][0];
        #pragma unroll
        for (int z = 0; z < 3; z++) {
            const bh* wz = Wf + (((size_t)z * 8 + nt) * 8 + (k32 >> 1)) * 4096
                         + (size_t)((k32 & 1) * 4 + wave) * 512;
            gload16(wz + lane * 8, &Wl[z * 2048 + wave * 512 + lane * 8]);
        }
    };

    float4 ax0 = *(const float4*)&xrow[0];
    float4 ax1 = *(const float4*)&xrow[4];
    stageW(0, 0);
    for (int k32 = 0; k32 < 16; k32++) {
        const int buf = k32 & 1;
        __syncthreads();                  // W(k32) landed; other buf free
        if (k32 < 15) stageW(k32 + 1, buf ^ 1);
        const int kn = (k32 < 15) ? (k32 + 1) * 32 : 15 * 32;   // clamped (discarded on last)
        float4 nx0 = *(const float4*)&xrow[kn];
        float4 nx1 = *(const float4*)&xrow[kn + 4];
        bf16x8 af = pk_bf8(ax0.x, ax0.y, ax0.z, ax0.w,
                           ax1.x, ax1.y, ax1.z, ax1.w);
        const bh* Wl = &smem[buf][0];
        #pragma unroll
        for (int z = 0; z < 3; z++)
            #pragma unroll
            for (int fn = 0; fn < 4; fn++) {
                bf16x8 bf = *(const bf16x8*)&Wl[z * 2048 + fn * 512 + lane * 8];
                acc[z][fn] = mfma_bf16(af, bf, acc[z][fn]);
            }
        ax0 = nx0; ax1 = nx1;
    }
    __syncthreads();                      // drain before LDS reuse in epilogue

    const int h = nt;
    const int b = m0 >> 12;
    const int l0 = m0 & 4095;
    const int bh_i = b * NH + h;
    const int kt0 = l0 >> 6;              // exactly one 64-row kt tile per block

    // ---- Phase Q: LDS transpose, coalesced 16B stores to row-major Qb.
    {
        bh* Tq = &smem[0][0];             // 64 x 68 (4352 elems, fits)
        #pragma unroll
        for (int i = 0; i < 4; i++) {
            int ll = wave * 16 + quad * 4 + i;
            #pragma unroll
            for (int fn = 0; fn < 4; fn++)
                Tq[ll * 68 + fn * 16 + c16] =
                    __float2bfloat16(acc[0][fn][i] * 0.125f);
        }
        __syncthreads();
        int l = t >> 2, part = t & 3;
        bh* dst = Qb + ((size_t)bh_i * NL + l0 + l) * NDH + part * 16;
        const bh* src = &Tq[l * 68 + part * 16];
        *(i32x4*)(dst)     = *(const i32x4*)(src);
        *(i32x4*)(dst + 8) = *(const i32x4*)(src + 8);
        __syncthreads();
    }

    // ---- Phase K: LDS scatter into the kt0 K-frag image (xLOG2E), copy-out.
    {
        bh* Tk = &smem[0][0];             // 4096 elems = one kt K-image
        #pragma unroll
        for (int i = 0; i < 4; i++) {
            int c16t = quad * 4 + i;      // key-within-16; fk = wave
            #pragma unroll
            for (int fn = 0; fn < 4; fn++) {
                int d = fn * 16 + c16;
                int kc = d >> 5, qt = (d >> 3) & 3, j = d & 7;
                Tk[(wave * 2 + kc) * 512 + (qt * 16 + c16t) * 8 + j] =
                    __float2bfloat16(acc[1][fn][i] * LOG2E);
            }
        }
        __syncthreads();
        int idx = t * 16;
        bh* dst = KVf + (size_t)(bh_i * 64 + kt0) * KVBLK + idx;
        *(i32x4*)(dst)     = *(const i32x4*)&Tk[idx];
        *(i32x4*)(dst + 8) = *(const i32x4*)&Tk[idx + 8];
    }

    // ---- V: 32-k interleaved frag stores (same sigma-image); fkv = wave.
    #pragma unroll
    for (int fn = 0; fn < 4; fn++) {
        size_t addr = (size_t)(bh_i * 64 + kt0) * KVBLK + 4096
                    + (size_t)(fn * 2 + (wave >> 1)) * 512 + lane * 8 + (wave & 1) * 4;
        st_bf4(&KVf[addr], acc[2][fn][0], acc[2][fn][1],
                           acc[2][fn][2], acc[2][fn][3]);
    }
}

// ---------------------------------------------------------------------------
// Kernel 2: flash attention — unchanged from R6/R7 (verified): split-K, 512
// threads, K=32 PV via pre-permuted V image, XCD-chunked work swizzle.
// ---------------------------------------------------------------------------
__global__ __launch_bounds__(512, 4)
void flash_attn(const bh* __restrict__ Qb, const bh* __restrict__ KVf,
                bh* __restrict__ attb)
{
    __shared__ __align__(16) bh SF[2][2][KVBLK];   // [group][buf], 64 KB

    const int t = threadIdx.x;
    const int wave = t >> 6, lane = t & 63;
    const int group = wave >> 2, w4 = wave & 3;
    const int quad = lane >> 4, c16 = lane & 15;

    const int bid = blockIdx.x + blockIdx.y * 32;      // gridDim.x == 32
    const int work = (bid & 7) * 64 + (bid >> 3);      // bijective on [0,512)
    const int bh_idx = work >> 5;
    const int q0 = (work & 31) * 128;

    const bh* Qp  = Qb + (size_t)bh_idx * NL * NDH;
    const bh* KVp = KVf + (size_t)bh_idx * 64 * KVBLK;

    bf16x8 qf[2][2];
    #pragma unroll
    for (int fq = 0; fq < 2; fq++)
        #pragma unroll
        for (int kc = 0; kc < 2; kc++)
            qf[fq][kc] = *(const bf16x8*)
                &Qp[(size_t)(q0 + w4 * 32 + fq * 16 + c16) * NDH + kc * 32 + quad * 8];

    f32x4 ot[4][2];
    float lsum[2] = {0.0f, 0.0f};
    for (int a = 0; a < 4; a++)
        for (int fq = 0; fq < 2; fq++)
            for (int u = 0; u < 4; u++) ot[a][fq][u] = 0.0f;
    const f32x4 z4 = {0.0f, 0.0f, 0.0f, 0.0f};

    auto stage = [&](int i, int buf) {
        int kt = 2 * i + group;
        #pragma unroll
        for (int r = 0; r < 4; r++) {
            int off = (w4 * 4 + r) * 512 + lane * 8;
            gload16(KVp + (size_t)kt * KVBLK + off, &SF[group][buf][off]);
        }
    };

    stage(0, 0);
    for (int i = 0; i < 32; i++) {
        const int buf = i & 1;
        __syncthreads();
        if (i < 31) stage(i + 1, buf ^ 1);
        const bh* sf = &SF[group][buf][0];

        f32x4 s[4][2];
        #pragma unroll
        for (int fk = 0; fk < 4; fk++) {
            bf16x8 kf0 = *(const bf16x8*)&sf[(fk * 2 + 0) * 512 + lane * 8];
            s[fk][0] = mfma_bf16(kf0, qf[0][0], z4);
            s[fk][1] = mfma_bf16(kf0, qf[1][0], z4);
        }
        #pragma unroll
        for (int fk = 0; fk < 4; fk++) {
            bf16x8 kf1 = *(const bf16x8*)&sf[(fk * 2 + 1) * 512 + lane * 8];
            s[fk][0] = mfma_bf16(kf1, qf[0][1], s[fk][0]);
            s[fk][1] = mfma_bf16(kf1, qf[1][1], s[fk][1]);
        }

        bf16x8 vt[4][2];
        #pragma unroll
        for (int fn = 0; fn < 4; fn++)
            #pragma unroll
            for (int a = 0; a < 2; a++)
                vt[fn][a] = *(const bf16x8*)&sf[4096 + (fn * 2 + a) * 512 + lane * 8];

        float rs0 = 0.0f, rs1 = 0.0f;
        #pragma unroll
        for (int a = 0; a < 2; a++) {
            float a0 = __builtin_amdgcn_exp2f(s[2 * a][0][0]);
            float a1 = __builtin_amdgcn_exp2f(s[2 * a][0][1]);
            float a2 = __builtin_amdgcn_exp2f(s[2 * a][0][2]);
            float a3 = __builtin_amdgcn_exp2f(s[2 * a][0][3]);
            float a4 = __builtin_amdgcn_exp2f(s[2 * a + 1][0][0]);
            float a5 = __builtin_amdgcn_exp2f(s[2 * a + 1][0][1]);
            float a6 = __builtin_amdgcn_exp2f(s[2 * a + 1][0][2]);
            float a7 = __builtin_amdgcn_exp2f(s[2 * a + 1][0][3]);
            rs0 += ((a0 + a1) + (a2 + a3)) + ((a4 + a5) + (a6 + a7));
            bf16x8 p0 = pk_bf8(a0, a1, a2, a3, a4, a5, a6, a7);
            float b0 = __builtin_amdgcn_exp2f(s[2 * a][1][0]);
            float b1 = __builtin_amdgcn_exp2f(s[2 * a][1][1]);
            float b2 = __builtin_amdgcn_exp2f(s[2 * a][1][2]);
            float b3 = __builtin_amdgcn_exp2f(s[2 * a][1][3]);
            float b4 = __builtin_amdgcn_exp2f(s[2 * a + 1][1][0]);
            float b5 = __builtin_amdgcn_exp2f(s[2 * a + 1][1][1]);
            float b6 = __builtin_amdgcn_exp2f(s[2 * a + 1][1][2]);
            float b7 = __builtin_amdgcn_exp2f(s[2 * a + 1][1][3]);
            rs1 += ((b0 + b1) + (b2 + b3)) + ((b4 + b5) + (b6 + b7));
            bf16x8 p1 = pk_bf8(b0, b1, b2, b3, b4, b5, b6, b7);
            #pragma unroll
            for (int fn = 0; fn < 4; fn++) {
                ot[fn][0] = mfma_bf16(vt[fn][a], p0, ot[fn][0]);
                ot[fn][1] = mfma_bf16(vt[fn][a], p1, ot[fn][1]);
            }
        }
        lsum[0] += rs0;
        lsum[1] += rs1;
    }

    #pragma unroll
    for (int fq = 0; fq < 2; fq++) {
        lsum[fq] += __shfl_xor(lsum[fq], 16);
        lsum[fq] += __shfl_xor(lsum[fq], 32);
    }

    float* Ocmb = (float*)&SF[0][0][0];
    float* Lcmb = Ocmb + 128 * 64;
    __syncthreads();
    if (group == 1) {
        #pragma unroll
        for (int fq = 0; fq < 2; fq++) {
            int q = w4 * 32 + fq * 16 + c16;
            #pragma unroll
            for (int fn = 0; fn < 4; fn++)
                *(f32x4*)&Ocmb[q * 64 + fn * 16 + quad * 4] = ot[fn][fq];
            if (quad == 0) Lcmb[q] = lsum[fq];
        }
    }
    __syncthreads();
    if (group == 0) {
        const int b = bh_idx >> 3, h = bh_idx & 7;
        const int mbase16 = (b * NL + q0) >> 4;
        #pragma unroll
        for (int fq = 0; fq < 2; fq++) {
            int q = w4 * 32 + fq * 16 + c16;
            float inv = 1.0f / (lsum[fq] + Lcmb[q]);
            int m16 = mbase16 + w4 * 2 + fq;
            #pragma unroll
            for (int fn = 0; fn < 4; fn++) {
                f32x4 o2 = *(const f32x4*)&Ocmb[q * 64 + fn * 16 + quad * 4];
                size_t addr = ((size_t)m16 * 16 + h * 2 + (fn >> 1)) * 512
                            + (size_t)(((fn & 1) * 2 + (quad >> 1)) * 16 + c16) * 8
                            + (quad & 1) * 4;
                st_bf4(&attb[addr],
                       (ot[fn][fq][0] + o2[0]) * inv, (ot[fn][fq][1] + o2[1]) * inv,
                       (ot[fn][fq][2] + o2[2]) * inv, (ot[fn][fq][3] + o2[3]) * inv);
            }
        }
    }
}

// ---------------------------------------------------------------------------
// Kernel 3: out_gemm v3 — A-frags loaded DIRECTLY from attb into registers
// (16B per lane, already bf16 A-frag image); only W staged in LDS.
// Reg double-buffer across the K-loop.  Epilogue verbatim R7.
// ---------------------------------------------------------------------------
__global__ __launch_bounds__(256, 4)
void out_gemm(const bh* __restrict__ Af, const bh* __restrict__ Wf,
              const float* __restrict__ bo, float* __restrict__ out)
{
    __shared__ __align__(16) bh smem[2][2048];   // W only: 4 KB per buf

    const int t = threadIdx.x;
    const int wave = t >> 6, lane = t & 63;
    const int quad = lane >> 4, c16 = lane & 15;
    const int m0 = blockIdx.x * 64;
    const int nt = blockIdx.y;
    const int n0 = nt * 64;
    const int m16b = m0 >> 4;

    const bh* arow = Af + ((size_t)(m16b + wave) * 16) * 512 + lane * 8;

    f32x4 acc[4];
    for (int fn = 0; fn < 4; fn++)
        for (int u = 0; u < 4; u++) acc[fn][u] = 0.0f;

    auto stageW = [&](int k32, int buf) {
        const bh* wz = Wf + (((size_t)3 * 8 + nt) * 8 + (k32 >> 1)) * 4096
                     + (size_t)((k32 & 1) * 4 + wave) * 512;
        gload16(wz + lane * 8, &smem[buf][wave * 512 + lane * 8]);
    };

    i32x4 axc = *(const i32x4*)&arow[0];
    stageW(0, 0);
    for (int k32 = 0; k32 < 16; k32++) {
        const int buf = k32 & 1;
        __syncthreads();
        if (k32 < 15) stageW(k32 + 1, buf ^ 1);
        const int kn = (k32 < 15) ? (k32 + 1) : 15;
        i32x4 axn = *(const i32x4*)&arow[(size_t)kn * 512];
        bf16x8 af = *(const bf16x8*)&axc;
        const bh* Wl = &smem[buf][0];
        #pragma unroll
        for (int fn = 0; fn < 4; fn++) {
            bf16x8 bf = *(const bf16x8*)&Wl[fn * 512 + lane * 8];
            acc[fn] = mfma_bf16(af, bf, acc[fn]);
        }
        axc = axn;
    }

    #pragma unroll
    for (int i = 0; i < 4; i++) {
        int mr = m0 + wave * 16 + quad * 4 + i;
        #pragma unroll
        for (int fn = 0; fn < 4; fn++) {
            int cn = n0 + fn * 16 + c16;
            out[(size_t)mr * 512 + cn] = acc[fn][i] + bo[cn];
        }
    }
}

// ---------------------------------------------------------------------------
extern "C" void kernel_launch(void* const* d_in, const int* in_sizes, int n_in,
                              void* d_out, int out_size, void* d_ws, size_t ws_size,
                              hipStream_t stream)
{
    const float* x  = (const float*)d_in[0];
    const float* Wq = (const float*)d_in[1];
    const float* Wk = (const float*)d_in[2];
    const float* Wv = (const float*)d_in[3];
    const float* Wo = (const float*)d_in[4];
    const float* bo = (const float*)d_in[5];
    float* out = (float*)d_out;

    const size_t mat = (size_t)NM * NC;       // 4 Mi elems (8 MB bf16)
    bh* Qb   = (bh*)d_ws;                     //  8 MB
    bh* KVf  = Qb + mat;                      // 16 MB
    bh* attb = KVf + 2 * mat;                 //  8 MB (A-frag layout)
    bh* Wf   = attb + mat;                    //  2 MB

    prep      <<<dim3(64, 1, 1),          256, 0, stream>>>(Wq, Wk, Wv, Wo, Wf);
    qkv_gemm  <<<dim3(NM / 64, NC / 64),  256, 0, stream>>>(x, Wf, Qb, KVf);
    flash_attn<<<dim3(NL / 128, NB * NH), 512, 0, stream>>>(Qb, KVf, attb);
    out_gemm  <<<dim3(NM / 64, NC / 64),  256, 0, stream>>>(attb, Wf, bo, out);
}